// Round 4
// baseline (212.929 us; speedup 1.0000x reference)
//
#include <hip/hip_runtime.h>
#include <math.h>

// B=4, S=4096, D=2048, E=64, K=2
#define NTOK    16384
#define DDIM    2048
#define NEXP    64
#define PSTRIDE (NTOK * NEXP)      // floats per logit plane / output plane
#define KSPLIT  4
#define KRANGE  512                // k per block
#define NPH     8                  // phases of 64 k per block
#define WSLICE  16384              // W slice bytes: 2 planes x 64 e x 64 k x 2 B
#define PART_OFF (1 << 20)         // partials at d_ws + 1 MB

#define AS1 __attribute__((address_space(1)))
#define AS3 __attribute__((address_space(3)))

typedef _Float16 half8   __attribute__((ext_vector_type(8)));
typedef float    floatx4 __attribute__((ext_vector_type(4)));

// ---------------------------------------------------------------------------
// W (fp32 [64][2048]) -> d_ws: 32 slices (64 k each) of 16 KB, linear-DMA
// order with XOR chunk swizzle: slice p, chunk L = plane*512 + e*8 + c',
// holding source k-chunk c = c' ^ (e&7), k = p*64 + c*8.
// hi plane = (f16)w, lo = (f16)((w-hi)*2048).  (round-2 layout, known-good)
// ---------------------------------------------------------------------------
__global__ __launch_bounds__(256) void wconv_kernel(
    const float* __restrict__ W, _Float16* __restrict__ ws)
{
    const int g     = blockIdx.x * 256 + threadIdx.x;   // 32768 chunks
    const int p     = g >> 10;
    const int L     = g & 1023;
    const int plane = L >> 9;
    const int e     = (L >> 3) & 63;
    const int cp    = L & 7;
    const int c     = cp ^ (e & 7);
    const int k     = (p << 6) + (c << 3);

    const float* src = &W[(size_t)e * DDIM + k];
    floatx4 w0 = *(const floatx4*)src;
    floatx4 w1 = *(const floatx4*)(src + 4);

    half8 o;
#pragma unroll
    for (int i = 0; i < 4; ++i) {
        float f0 = w0[i], f1 = w1[i];
        _Float16 h0 = (_Float16)f0, h1 = (_Float16)f1;
        if (plane == 0) { o[i] = h0; o[4 + i] = h1; }
        else {
            o[i]     = (_Float16)((f0 - (float)h0) * 2048.0f);
            o[4 + i] = (_Float16)((f1 - (float)h1) * 2048.0f);
        }
    }
    *(half8*)((char*)ws + (size_t)g * 16) = o;
}

// ---------------------------------------------------------------------------
// Split-K GEMM: block (tg, sp) computes partial logits for tokens
// [tg*64, tg*64+64) over k in [sp*512, sp*512+512).  256 thr, 4 waves = 4
// token tiles of 16 rows; each wave does full E=64 for its rows (no
// cross-wave reduce).  W staged via global_load_lds (16 KB/phase, dbuf,
// counted vmcnt); x loaded direct to registers, double-buffered.
// Grid 1024 = 4 blocks/CU; bx = sp*256+tg puts all splits of a token group
// on one XCD (x shared in that L2).
// ---------------------------------------------------------------------------
__global__ __launch_bounds__(256, 4) void gemm_kernel(
    const float* __restrict__ x,
    const _Float16* __restrict__ ws,
    float* __restrict__ part)
{
    __shared__ _Float16 lw[2][8192];   // 2 x 16 KB W slices

    const int tid  = threadIdx.x;
    const int lane = tid & 63;
    const int wid  = tid >> 6;         // 0..3 token tile
    const int sp   = blockIdx.x >> 8;  // k split 0..3
    const int tg   = blockIdx.x & 255; // token group
    const int t0b  = tg * 64;
    const int mrow = lane & 15;        // A token row / B expert row
    const int quad = lane >> 4;

    floatx4 acc_hh[4], acc_md[4];
#pragma unroll
    for (int j = 0; j < 4; ++j) { acc_hh[j] = (floatx4)0.0f; acc_md[j] = (floatx4)0.0f; }

    // W DMA source: pre-swizzled linear slices; wave wid copies 4 KB/phase.
    const char* gw0 = (const char*)ws + (size_t)(sp * NPH) * WSLICE
                    + wid * 4096 + lane * 16;
    // x: lane's row pointer at this split's k base.
    const float* xrow = x + (size_t)(t0b + wid * 16 + mrow) * DDIM
                      + sp * KRANGE + quad * 8;

#define STAGE(Q, BUF)                                                          \
    {                                                                          \
        const char* gsw = gw0 + (size_t)(Q) * WSLICE;                          \
        char*       ldw = (char*)&lw[BUF][0] + wid * 4096;                     \
        _Pragma("unroll")                                                      \
        for (int i = 0; i < 4; ++i)                                            \
            __builtin_amdgcn_global_load_lds(                                  \
                (const AS1 unsigned int*)(const void*)(gsw + i * 1024),        \
                (AS3 unsigned int*)(void*)(ldw + i * 1024), 16, 0, 0);         \
    }

#define LOADX(XV, Q)                                                           \
    {                                                                          \
        const float* xp = xrow + (Q) * 64;                                     \
        XV[0] = *(const floatx4*)(xp);                                         \
        XV[1] = *(const floatx4*)(xp + 4);                                     \
        XV[2] = *(const floatx4*)(xp + 32);                                    \
        XV[3] = *(const floatx4*)(xp + 36);                                    \
    }

#define COMPUTE(BUF, XV)                                                       \
    {                                                                          \
        const _Float16* wb = &lw[BUF][0];                                      \
        _Pragma("unroll")                                                      \
        for (int s = 0; s < 2; ++s) {                                          \
            half8 a_hi, a_lo;                                                  \
            _Pragma("unroll")                                                  \
            for (int i = 0; i < 4; ++i) {                                      \
                float f0 = XV[2 * s][i], f1 = XV[2 * s + 1][i];                \
                _Float16 h0 = (_Float16)f0, h1 = (_Float16)f1;                 \
                a_hi[i]     = h0; a_lo[i]     = (_Float16)((f0 - (float)h0) * 2048.0f); \
                a_hi[4 + i] = h1; a_lo[4 + i] = (_Float16)((f1 - (float)h1) * 2048.0f); \
            }                                                                  \
            _Pragma("unroll")                                                  \
            for (int j = 0; j < 4; ++j) {                                      \
                const int e   = j * 16 + mrow;                                 \
                const int ck  = s * 4 + quad;                                  \
                const int off = e * 64 + ((ck ^ (e & 7)) << 3);                \
                half8 bh = *(const half8*)(wb + off);                          \
                half8 bl = *(const half8*)(wb + 4096 + off);                   \
                acc_hh[j] = __builtin_amdgcn_mfma_f32_16x16x32_f16(a_hi, bh, acc_hh[j], 0, 0, 0); \
                acc_md[j] = __builtin_amdgcn_mfma_f32_16x16x32_f16(a_hi, bl, acc_md[j], 0, 0, 0); \
                acc_md[j] = __builtin_amdgcn_mfma_f32_16x16x32_f16(a_lo, bh, acc_md[j], 0, 0, 0); \
            }                                                                  \
        }                                                                      \
    }

    floatx4 xa[4], xb[4];

    // prologue: phase 0 W + x in flight (8 vmem ops)
    STAGE(0, 0)
    LOADX(xa, 0)

#pragma unroll 1
    for (int q = 0; q < NPH; q += 2) {
        // even phase q: reads xa + lw[0]; issues phase q+1 (8 ops)
        STAGE(q + 1, 1)
        LOADX(xb, q + 1)
        asm volatile("s_waitcnt vmcnt(8)" ::: "memory");
        __builtin_amdgcn_s_barrier();
        asm volatile("" ::: "memory");
        COMPUTE(0, xa)
        __builtin_amdgcn_s_barrier();
        asm volatile("" ::: "memory");

        // odd phase q+1: reads xb + lw[1]; issues phase q+2 unless last
        if (q < NPH - 2) {
            STAGE(q + 2, 0)
            LOADX(xa, q + 2)
            asm volatile("s_waitcnt vmcnt(8)" ::: "memory");
        } else {
            asm volatile("s_waitcnt vmcnt(0)" ::: "memory");
        }
        __builtin_amdgcn_s_barrier();
        asm volatile("" ::: "memory");
        COMPUTE(1, xb)
        __builtin_amdgcn_s_barrier();
        asm volatile("" ::: "memory");
    }

    // ---- epilogue: write partial logits (wave-local, no reduce) ----
    float* pb = part + (size_t)sp * PSTRIDE;
#pragma unroll
    for (int j = 0; j < 4; ++j)
#pragma unroll
        for (int r = 0; r < 4; ++r) {
            const float v = acc_hh[j][r] + acc_md[j][r] * (1.0f / 2048.0f);
            const int trow = t0b + wid * 16 + quad * 4 + r;
            pb[(size_t)trow * NEXP + j * 16 + mrow] = v;
        }
}

// ---------------------------------------------------------------------------
// Finish: one thread per token.  Sum 4 partials + bias, softmax, stable
// top-2 (tie -> lower index), write masks | probs.
// ---------------------------------------------------------------------------
__global__ __launch_bounds__(64) void finish_kernel(
    const float* __restrict__ part,
    const float* __restrict__ bias,
    float* __restrict__ out)
{
    const int t = blockIdx.x * 64 + threadIdx.x;
    const float* p0 = part + (size_t)t * NEXP;

    float lg[NEXP];
#pragma unroll
    for (int c = 0; c < 16; ++c) {
        floatx4 v = *(const floatx4*)(p0 + c * 4);
#pragma unroll
        for (int sp = 1; sp < KSPLIT; ++sp)
            v += *(const floatx4*)(p0 + (size_t)sp * PSTRIDE + c * 4);
        v += *(const floatx4*)(bias + c * 4);
#pragma unroll
        for (int i = 0; i < 4; ++i) lg[c * 4 + i] = v[i];
    }

    float m = lg[0];
#pragma unroll
    for (int e = 1; e < NEXP; ++e) m = fmaxf(m, lg[e]);

    float pr[NEXP], s = 0.0f;
#pragma unroll
    for (int e = 0; e < NEXP; ++e) { pr[e] = __expf(lg[e] - m); s += pr[e]; }
    const float rinv = 1.0f / s;

    float v1 = -1e30f, v2 = -1e30f; int i1 = -1, i2 = -1;
#pragma unroll
    for (int e = 0; e < NEXP; ++e) {
        const float v = lg[e];
        if (v > v1)      { v2 = v1; i2 = i1; v1 = v; i1 = e; }
        else if (v > v2) { v2 = v;  i2 = e; }
    }

    float* om = out + (size_t)t * NEXP;
    float* op = out + PSTRIDE + (size_t)t * NEXP;
#pragma unroll
    for (int c = 0; c < 16; ++c) {
        floatx4 mv, pv;
#pragma unroll
        for (int i = 0; i < 4; ++i) {
            const int e = c * 4 + i;
            mv[i] = (e == i1 || e == i2) ? 1.0f : 0.0f;
            pv[i] = pr[e] * rinv;
        }
        *(floatx4*)(om + c * 4) = mv;
        *(floatx4*)(op + c * 4) = pv;
    }
}

extern "C" void kernel_launch(void* const* d_in, const int* in_sizes, int n_in,
                              void* d_out, int out_size, void* d_ws, size_t ws_size,
                              hipStream_t stream) {
    const float* x = (const float*)d_in[0];   // [4,4096,2048] f32
    const float* W = (const float*)d_in[1];   // [64,2048] f32
    const float* b = (const float*)d_in[2];   // [64] f32
    (void)in_sizes; (void)n_in; (void)out_size; (void)ws_size;
    float* out = (float*)d_out;               // [masks | probs]

    _Float16* ws   = (_Float16*)d_ws;                       // 512 KB W planes
    float*    part = (float*)((char*)d_ws + PART_OFF);      // 4 x 4 MB partials

    hipLaunchKernelGGL(wconv_kernel, dim3(128), dim3(256), 0, stream, W, ws);
    hipLaunchKernelGGL(gemm_kernel, dim3(256 * KSPLIT), dim3(256), 0, stream, x, ws, part);
    hipLaunchKernelGGL(finish_kernel, dim3(NTOK / 64), dim3(64), 0, stream, part, b, out);
}

// Round 5
// 210.695 us; speedup vs baseline: 1.0106x; 1.0106x over previous
//
#include <hip/hip_runtime.h>
#include <math.h>

// B=4, S=4096, D=2048, E=64, K=2
#define NTOK    16384
#define DDIM    2048
#define NEXP    64
#define PSTRIDE (NTOK * NEXP)      // floats per logit plane / output plane
#define KSPLIT  4
#define KRANGE  512                // k per block
#define NPH     8                  // phases of 64 k per block
#define TOKB    128                // tokens per block
#define WSLICE  16384              // W slice bytes: 2 planes x 64 e x 64 k x 2 B
#define PART_OFF (1 << 20)         // partials at d_ws + 1 MB

#define AS1 __attribute__((address_space(1)))
#define AS3 __attribute__((address_space(3)))

typedef _Float16 half8   __attribute__((ext_vector_type(8)));
typedef float    floatx4 __attribute__((ext_vector_type(4)));

// ---------------------------------------------------------------------------
// W (fp32 [64][2048]) -> d_ws: 32 slices (64 k each) of 16 KB, linear-DMA
// order with XOR chunk swizzle: slice p, chunk L = plane*512 + e*8 + c',
// holding source k-chunk c = c' ^ (e&7), k = p*64 + c*8.
// hi plane = (f16)w, lo = (f16)((w-hi)*2048).  (round-2/4 layout, known-good)
// ---------------------------------------------------------------------------
__global__ __launch_bounds__(256) void wconv_kernel(
    const float* __restrict__ W, _Float16* __restrict__ ws)
{
    const int g     = blockIdx.x * 256 + threadIdx.x;   // 32768 chunks
    const int p     = g >> 10;
    const int L     = g & 1023;
    const int plane = L >> 9;
    const int e     = (L >> 3) & 63;
    const int cp    = L & 7;
    const int c     = cp ^ (e & 7);
    const int k     = (p << 6) + (c << 3);

    const float* src = &W[(size_t)e * DDIM + k];
    floatx4 w0 = *(const floatx4*)src;
    floatx4 w1 = *(const floatx4*)(src + 4);

    half8 o;
#pragma unroll
    for (int i = 0; i < 4; ++i) {
        float f0 = w0[i], f1 = w1[i];
        _Float16 h0 = (_Float16)f0, h1 = (_Float16)f1;
        if (plane == 0) { o[i] = h0; o[4 + i] = h1; }
        else {
            o[i]     = (_Float16)((f0 - (float)h0) * 2048.0f);
            o[4 + i] = (_Float16)((f1 - (float)h1) * 2048.0f);
        }
    }
    *(half8*)((char*)ws + (size_t)g * 16) = o;
}

// ---------------------------------------------------------------------------
// Split-K GEMM: block (sp, tg) computes partial logits for tokens
// [tg*128, tg*128+128) over k in [sp*512, sp*512+512).  512 thr, 8 waves =
// 8 token tiles of 16 rows; each wave does full E=64 for its rows.
// W staged via global_load_lds (16 KB/phase dbuf, counted vmcnt(6));
// x loaded direct to registers (r0/r4-proven gather), double-buffered.
// Grid 512 = 2 blocks/CU, 16 waves/CU.  bx = sp*128+tg puts all 4 splits
// of a token group on one XCD (x shared in that L2).
// W-refetch total = 128 groups x 512 KB = 64 MB (was 128-256 MB).
// ---------------------------------------------------------------------------
__global__ __launch_bounds__(512, 4) void gemm_kernel(
    const float* __restrict__ x,
    const _Float16* __restrict__ ws,
    float* __restrict__ part)
{
    __shared__ _Float16 lw[2][8192];   // 2 x 16 KB W slices

    const int tid  = threadIdx.x;
    const int lane = tid & 63;
    const int wid  = tid >> 6;         // 0..7 token tile
    const int sp   = blockIdx.x >> 7;  // k split 0..3
    const int tg   = blockIdx.x & 127; // token group
    const int t0b  = tg * TOKB;
    const int mrow = lane & 15;        // A token row / B expert row
    const int quad = lane >> 4;

    floatx4 acc_hh[4], acc_md[4];
#pragma unroll
    for (int j = 0; j < 4; ++j) { acc_hh[j] = (floatx4)0.0f; acc_md[j] = (floatx4)0.0f; }

    // W DMA source: pre-swizzled linear slices; wave wid copies 2 KB/phase.
    const char* gw0 = (const char*)ws + (size_t)(sp * NPH) * WSLICE
                    + wid * 2048 + lane * 16;
    // x: lane's row pointer at this split's k base.
    const float* xrow = x + (size_t)(t0b + wid * 16 + mrow) * DDIM
                      + sp * KRANGE + quad * 8;

#define STAGE(Q, BUF)                                                          \
    {                                                                          \
        const char* gsw = gw0 + (size_t)(Q) * WSLICE;                          \
        char*       ldw = (char*)&lw[BUF][0] + wid * 2048;                     \
        __builtin_amdgcn_global_load_lds(                                      \
            (const AS1 unsigned int*)(const void*)(gsw),                       \
            (AS3 unsigned int*)(void*)(ldw), 16, 0, 0);                        \
        __builtin_amdgcn_global_load_lds(                                      \
            (const AS1 unsigned int*)(const void*)(gsw + 1024),                \
            (AS3 unsigned int*)(void*)(ldw + 1024), 16, 0, 0);                 \
    }

#define LOADX(XV, Q)                                                           \
    {                                                                          \
        const float* xp = xrow + (Q) * 64;                                     \
        XV[0] = *(const floatx4*)(xp);                                         \
        XV[1] = *(const floatx4*)(xp + 4);                                     \
        XV[2] = *(const floatx4*)(xp + 32);                                    \
        XV[3] = *(const floatx4*)(xp + 36);                                    \
    }

#define COMPUTE(BUF, XV)                                                       \
    {                                                                          \
        const _Float16* wb = &lw[BUF][0];                                      \
        _Pragma("unroll")                                                      \
        for (int s = 0; s < 2; ++s) {                                          \
            half8 a_hi, a_lo;                                                  \
            _Pragma("unroll")                                                  \
            for (int i = 0; i < 4; ++i) {                                      \
                float f0 = XV[2 * s][i], f1 = XV[2 * s + 1][i];                \
                _Float16 h0 = (_Float16)f0, h1 = (_Float16)f1;                 \
                a_hi[i]     = h0; a_lo[i]     = (_Float16)((f0 - (float)h0) * 2048.0f); \
                a_hi[4 + i] = h1; a_lo[4 + i] = (_Float16)((f1 - (float)h1) * 2048.0f); \
            }                                                                  \
            _Pragma("unroll")                                                  \
            for (int j = 0; j < 4; ++j) {                                      \
                const int e   = j * 16 + mrow;                                 \
                const int ck  = s * 4 + quad;                                  \
                const int off = e * 64 + ((ck ^ (e & 7)) << 3);                \
                half8 bh = *(const half8*)(wb + off);                          \
                half8 bl = *(const half8*)(wb + 4096 + off);                   \
                acc_hh[j] = __builtin_amdgcn_mfma_f32_16x16x32_f16(a_hi, bh, acc_hh[j], 0, 0, 0); \
                acc_md[j] = __builtin_amdgcn_mfma_f32_16x16x32_f16(a_hi, bl, acc_md[j], 0, 0, 0); \
                acc_md[j] = __builtin_amdgcn_mfma_f32_16x16x32_f16(a_lo, bh, acc_md[j], 0, 0, 0); \
            }                                                                  \
        }                                                                      \
    }

    floatx4 xa[4], xb[4];

    // prologue: phase 0 W + x in flight (6 vmem ops/wave)
    STAGE(0, 0)
    LOADX(xa, 0)

#pragma unroll 1
    for (int q = 0; q < NPH; q += 2) {
        // even phase q: reads xa + lw[0]; issues phase q+1 (6 ops)
        STAGE(q + 1, 1)
        LOADX(xb, q + 1)
        asm volatile("s_waitcnt vmcnt(6)" ::: "memory");
        __builtin_amdgcn_s_barrier();
        asm volatile("" ::: "memory");
        COMPUTE(0, xa)
        __builtin_amdgcn_s_barrier();
        asm volatile("" ::: "memory");

        // odd phase q+1: reads xb + lw[1]; issues phase q+2 unless last
        if (q < NPH - 2) {
            STAGE(q + 2, 0)
            LOADX(xa, q + 2)
            asm volatile("s_waitcnt vmcnt(6)" ::: "memory");
        } else {
            asm volatile("s_waitcnt vmcnt(0)" ::: "memory");
        }
        __builtin_amdgcn_s_barrier();
        asm volatile("" ::: "memory");
        COMPUTE(1, xb)
        __builtin_amdgcn_s_barrier();
        asm volatile("" ::: "memory");
    }

    // ---- epilogue: write partial logits (wave-local, no reduce) ----
    float* pb = part + (size_t)sp * PSTRIDE;
#pragma unroll
    for (int j = 0; j < 4; ++j)
#pragma unroll
        for (int r = 0; r < 4; ++r) {
            const float v = acc_hh[j][r] + acc_md[j][r] * (1.0f / 2048.0f);
            const int trow = t0b + wid * 16 + quad * 4 + r;
            pb[(size_t)trow * NEXP + j * 16 + mrow] = v;
        }
}

// ---------------------------------------------------------------------------
// Finish: one thread per token.  Sum 4 partials + bias, softmax, stable
// top-2 (tie -> lower index), write masks | probs.  (round-4, known-good)
// ---------------------------------------------------------------------------
__global__ __launch_bounds__(64) void finish_kernel(
    const float* __restrict__ part,
    const float* __restrict__ bias,
    float* __restrict__ out)
{
    const int t = blockIdx.x * 64 + threadIdx.x;
    const float* p0 = part + (size_t)t * NEXP;

    float lg[NEXP];
#pragma unroll
    for (int c = 0; c < 16; ++c) {
        floatx4 v = *(const floatx4*)(p0 + c * 4);
#pragma unroll
        for (int sp = 1; sp < KSPLIT; ++sp)
            v += *(const floatx4*)(p0 + (size_t)sp * PSTRIDE + c * 4);
        v += *(const floatx4*)(bias + c * 4);
#pragma unroll
        for (int i = 0; i < 4; ++i) lg[c * 4 + i] = v[i];
    }

    float m = lg[0];
#pragma unroll
    for (int e = 1; e < NEXP; ++e) m = fmaxf(m, lg[e]);

    float pr[NEXP], s = 0.0f;
#pragma unroll
    for (int e = 0; e < NEXP; ++e) { pr[e] = __expf(lg[e] - m); s += pr[e]; }
    const float rinv = 1.0f / s;

    float v1 = -1e30f, v2 = -1e30f; int i1 = -1, i2 = -1;
#pragma unroll
    for (int e = 0; e < NEXP; ++e) {
        const float v = lg[e];
        if (v > v1)      { v2 = v1; i2 = i1; v1 = v; i1 = e; }
        else if (v > v2) { v2 = v;  i2 = e; }
    }

    float* om = out + (size_t)t * NEXP;
    float* op = out + PSTRIDE + (size_t)t * NEXP;
#pragma unroll
    for (int c = 0; c < 16; ++c) {
        floatx4 mv, pv;
#pragma unroll
        for (int i = 0; i < 4; ++i) {
            const int e = c * 4 + i;
            mv[i] = (e == i1 || e == i2) ? 1.0f : 0.0f;
            pv[i] = pr[e] * rinv;
        }
        *(floatx4*)(om + c * 4) = mv;
        *(floatx4*)(op + c * 4) = pv;
    }
}

extern "C" void kernel_launch(void* const* d_in, const int* in_sizes, int n_in,
                              void* d_out, int out_size, void* d_ws, size_t ws_size,
                              hipStream_t stream) {
    const float* x = (const float*)d_in[0];   // [4,4096,2048] f32
    const float* W = (const float*)d_in[1];   // [64,2048] f32
    const float* b = (const float*)d_in[2];   // [64] f32
    (void)in_sizes; (void)n_in; (void)out_size; (void)ws_size;
    float* out = (float*)d_out;               // [masks | probs]

    _Float16* ws   = (_Float16*)d_ws;                       // 512 KB W planes
    float*    part = (float*)((char*)d_ws + PART_OFF);      // 4 x 4 MB partials

    hipLaunchKernelGGL(wconv_kernel, dim3(128), dim3(256), 0, stream, W, ws);
    hipLaunchKernelGGL(gemm_kernel, dim3(128 * KSPLIT), dim3(512), 0, stream, x, ws, part);
    hipLaunchKernelGGL(finish_kernel, dim3(NTOK / 64), dim3(64), 0, stream, part, b, out);
}